// Round 21
// baseline (65.380 us; speedup 1.0000x reference)
//
#include <hip/hip_runtime.h>

#define B_ 2
#define N_ 8192
#define K_ 16
#define C_ 64
#define PE_ 32
#define HID_ 16

typedef float f4 __attribute__((ext_vector_type(4)));

__device__ __forceinline__ f4 splat4(float x) { f4 r = {x, x, x, x}; return r; }
__device__ __forceinline__ f4 relu4(f4 v) {
  f4 r;
  r[0] = fmaxf(v[0], 0.f); r[1] = fmaxf(v[1], 0.f);
  r[2] = fmaxf(v[2], 0.f); r[3] = fmaxf(v[3], 0.f);
  return r;
}
__device__ __forceinline__ float dot4(float4 w, f4 v) {
  return fmaf(w.x, v[0], fmaf(w.y, v[1], fmaf(w.z, v[2], w.w * v[3])));
}

struct PK4 { f4 k0, k1, k2, k3; };

// pk[ii] = sum_j relu((Wd.c_ii + bd) - Wd.c_j), all 16 ii, named registers.
__device__ __forceinline__ PK4 channel(const float4* __restrict__ sq,
                                       int d, const float* __restrict__ Wpe,
                                       const float* __restrict__ bpe) {
  const float wx = Wpe[d * 3 + 0], wy = Wpe[d * 3 + 1], wz = Wpe[d * 3 + 2];
  const float wb = bpe[d];
  const float4 A0 = sq[0], B0 = sq[1], C0 = sq[2];
  const float4 A1 = sq[3], B1 = sq[4], C1 = sq[5];
  const float4 A2 = sq[6], B2 = sq[7], C2 = sq[8];
  const float4 A3 = sq[9], B3 = sq[10], C3 = sq[11];
  const float p0  = fmaf(wx, A0.x, fmaf(wy, A0.y, wz * A0.z));
  const float p1  = fmaf(wx, A0.w, fmaf(wy, B0.x, wz * B0.y));
  const float p2  = fmaf(wx, B0.z, fmaf(wy, B0.w, wz * C0.x));
  const float p3  = fmaf(wx, C0.y, fmaf(wy, C0.z, wz * C0.w));
  const float p4  = fmaf(wx, A1.x, fmaf(wy, A1.y, wz * A1.z));
  const float p5  = fmaf(wx, A1.w, fmaf(wy, B1.x, wz * B1.y));
  const float p6  = fmaf(wx, B1.z, fmaf(wy, B1.w, wz * C1.x));
  const float p7  = fmaf(wx, C1.y, fmaf(wy, C1.z, wz * C1.w));
  const float p8  = fmaf(wx, A2.x, fmaf(wy, A2.y, wz * A2.z));
  const float p9  = fmaf(wx, A2.w, fmaf(wy, B2.x, wz * B2.y));
  const float p10 = fmaf(wx, B2.z, fmaf(wy, B2.w, wz * C2.x));
  const float p11 = fmaf(wx, C2.y, fmaf(wy, C2.z, wz * C2.w));
  const float p12 = fmaf(wx, A3.x, fmaf(wy, A3.y, wz * A3.z));
  const float p13 = fmaf(wx, A3.w, fmaf(wy, B3.x, wz * B3.y));
  const float p14 = fmaf(wx, B3.z, fmaf(wy, B3.w, wz * C3.x));
  const float p15 = fmaf(wx, C3.y, fmaf(wy, C3.z, wz * C3.w));
  const f4 a0 = {p0 + wb, p1 + wb, p2 + wb, p3 + wb};
  const f4 a1 = {p4 + wb, p5 + wb, p6 + wb, p7 + wb};
  const f4 a2 = {p8 + wb, p9 + wb, p10 + wb, p11 + wb};
  const f4 a3 = {p12 + wb, p13 + wb, p14 + wb, p15 + wb};
  f4 k0 = splat4(0.f), k1 = splat4(0.f), k2 = splat4(0.f), k3 = splat4(0.f);
#define KSTEP(PJ)                                  \
  {                                                \
    const f4 sp = splat4(PJ);                      \
    k0 += relu4(a0 - sp); k1 += relu4(a1 - sp);    \
    k2 += relu4(a2 - sp); k3 += relu4(a3 - sp);    \
  }
  KSTEP(p0) KSTEP(p1) KSTEP(p2) KSTEP(p3) KSTEP(p4) KSTEP(p5) KSTEP(p6)
  KSTEP(p7) KSTEP(p8) KSTEP(p9) KSTEP(p10) KSTEP(p11) KSTEP(p12) KSTEP(p13)
  KSTEP(p14) KSTEP(p15)
#undef KSTEP
  PK4 r; r.k0 = k0; r.k1 = k1; r.k2 = k2; r.k3 = k3;
  return r;
}

// ---------------- Kernel 1 v3: LDS-staged coalesced f reads (R16/R20 verbatim)
__global__ __launch_bounds__(256) void k1v3(
    const float* __restrict__ f, const float* __restrict__ W1,
    const float* __restrict__ b1, float* __restrict__ ht) {
  __shared__ float sf[C_ * 20];            // [64][20] floats, 5120 B
  const int t = threadIdx.x;
  const int g0 = blockIdx.x * 16;
  const int b = g0 >> 13;
  const int n0 = g0 & (N_ - 1);
  {
    const int c = t >> 2, off = (t & 3) * 4;
    const f4 v = *reinterpret_cast<const f4*>(f + (size_t)(b * C_ + c) * N_ + n0 + off);
    *reinterpret_cast<f4*>(&sf[c * 20 + off]) = v;
  }
  __syncthreads();
  const int lane = t & 63;
  const int w = t >> 6;
  const f4* wp = reinterpret_cast<const f4*>(W1 + lane * C_);
  const f4 w0 = wp[0], w1 = wp[1], w2 = wp[2], w3 = wp[3];
  const f4 w4 = wp[4], w5 = wp[5], w6 = wp[6], w7 = wp[7];
  const f4 w8 = wp[8], w9 = wp[9], w10 = wp[10], w11 = wp[11];
  const f4 w12 = wp[12], w13 = wp[13], w14 = wp[14], w15 = wp[15];
  f4 a = splat4(0.f);
#define CSTEP(Q, E)                                                         \
  {                                                                         \
    const f4 fv = *reinterpret_cast<const f4*>(&sf[(Q * 4 + E) * 20 + w * 4]); \
    a += splat4(w##Q[E]) * fv;                                              \
  }
#define CQ(Q) CSTEP(Q, 0) CSTEP(Q, 1) CSTEP(Q, 2) CSTEP(Q, 3)
  CQ(0) CQ(1) CQ(2) CQ(3) CQ(4) CQ(5) CQ(6) CQ(7)
  CQ(8) CQ(9) CQ(10) CQ(11) CQ(12) CQ(13) CQ(14) CQ(15)
#undef CQ
#undef CSTEP
  const float bias = b1[lane];
  #pragma unroll
  for (int pt = 0; pt < 4; ++pt)
    ht[(size_t)(b * N_ + n0 + w * 4 + pt) * C_ + lane] = fmaxf(a[pt] + bias, 0.f);
}

// ---------------- Kernel 2+3, block-range split. P2 v3: barrier-free
// in-register k-reduction (lane=c holds all 16 k), ONE barrier total
// (before the coalesced fout write). P3 verbatim.
#define NP2 1024
__global__ __launch_bounds__(256) void k23_split(
    const float* __restrict__ p, const float* __restrict__ pe,
    const float* __restrict__ ht, const int* __restrict__ knn,
    const float* __restrict__ Wpe, const float* __restrict__ bpe,
    const float* __restrict__ Wh1, const float* __restrict__ bh1,
    const float* __restrict__ Wh2, const float* __restrict__ bh2,
    float* __restrict__ fout, float* __restrict__ delta) {
  __shared__ __align__(16) char smem[17920];
  const int t = threadIdx.x;

  if (blockIdx.x < NP2) {
    // ============ P2 v3: fout = max_k(pe + gathered ht), 16 pts/block =======
    // lane = c; wave w owns points n0b+w*4 .. +3. All 80 loads per wave
    // (4 pts x (4 pe f4 + 16 ht)) independent -> deep memory pipelining,
    // no __syncthreads until the final write staging.
    float* sout = (float*)smem;              // [64][18] floats, 4608 B
    const int base = blockIdx.x * 16;
    const int b = base >> 13;
    const int n0b = base & (N_ - 1);
    const int lane = t & 63;
    const int w = t >> 6;
    #pragma unroll
    for (int pt = 0; pt < 4; ++pt) {
      const int n = n0b + w * 4 + pt;
      const int* kn = knn + (size_t)(b * N_ + n) * K_;   // wave-uniform s_load
      const f4* per = reinterpret_cast<const f4*>(
          pe + ((size_t)(b * C_ + lane) * N_ + n) * K_);
      const f4 q0 = per[0], q1 = per[1], q2 = per[2], q3 = per[3];
      float mx = -3.402823466e+38f;
      #pragma unroll
      for (int k = 0; k < K_; ++k) {
        const float hv = ht[(size_t)(b * N_ + kn[k]) * C_ + lane];  // L2-hit
        const float pv = (k < 4) ? q0[k & 3] : (k < 8) ? q1[k & 3]
                        : (k < 12) ? q2[k & 3] : q3[k & 3];  // static (unrolled)
        mx = fmaxf(mx, pv + hv);
      }
      sout[lane * 18 + w * 4 + pt] = mx;     // stride 18 -> 2-way bank (free)
    }
    __syncthreads();                          // the ONLY barrier in P2
    const int c = t >> 2, q = t & 3;
    const float4 r = make_float4(sout[c * 18 + q * 4 + 0], sout[c * 18 + q * 4 + 1],
                                 sout[c * 18 + q * 4 + 2], sout[c * 18 + q * 4 + 3]);
    *reinterpret_cast<float4*>(fout + (size_t)(b * C_ + c) * N_ + n0b + q * 4) = r;
    return;
  }

  // ================= P3: KDE offset generator (R16/R20 verbatim) ==========
  {
    float* spk = (float*)smem;               // [8][16][32] quad-swizzled, 16 KB
    float* sc = (float*)(smem + 16384);      // [8][48] coords
    const int base = (blockIdx.x - NP2) * 8;
    const int b = base >> 13;
    const int g = t >> 5;
    const int l = t & 31;

    if (l < 16) {
      const int gid = base + g;
      const int idx = knn[(size_t)gid * K_ + l];
      const float* pp = p + (size_t)(b * N_ + idx) * 3;
      sc[g * 48 + l * 3 + 0] = pp[0];
      sc[g * 48 + l * 3 + 1] = pp[1];
      sc[g * 48 + l * 3 + 2] = pp[2];
    }
    __syncthreads();

    {
      const int d = l;
      const float4* sq = reinterpret_cast<const float4*>(&sc[g * 48]);
      const PK4 ck = channel(sq, d, Wpe, bpe);
      const int qw = d >> 2, pos = d & 3;
      float* gbase = spk + g * 512;
#define PKW(II, KV) \
      gbase[(II) * 32 + (((qw ^ ((II) & 7)) << 2) | pos)] = ck.KV[(II) & 3];
      PKW(0, k0) PKW(1, k0) PKW(2, k0) PKW(3, k0)
      PKW(4, k1) PKW(5, k1) PKW(6, k1) PKW(7, k1)
      PKW(8, k2) PKW(9, k2) PKW(10, k2) PKW(11, k2)
      PKW(12, k3) PKW(13, k3) PKW(14, k3) PKW(15, k3)
#undef PKW
    }
    __syncthreads();

    {
      const int i = t & 15, half = (t >> 4) & 1;
      const int gid = base + g;
      const float ci0 = sc[g * 48 + i * 3 + 0];
      const float ci1 = sc[g * 48 + i * 3 + 1];
      const float ci2 = sc[g * 48 + i * 3 + 2];
      const float4* sq = reinterpret_cast<const float4*>(&sc[g * 48]);
      const float INV2S = 0.49999975f;
      const float COEF = 0.39894225f;
      float kacc = 0.f;
      #pragma unroll
      for (int jj = 0; jj < 2; ++jj) {
        const int j4 = half * 2 + jj;
        const float4 a = sq[j4 * 3 + 0], b4 = sq[j4 * 3 + 1], c4 = sq[j4 * 3 + 2];
        float dx, dy, dz;
        dx = ci0 - a.x;  dy = ci1 - a.y;  dz = ci2 - a.z;
        kacc += __expf(-(dx * dx + dy * dy + dz * dz) * INV2S);
        dx = ci0 - a.w;  dy = ci1 - b4.x; dz = ci2 - b4.y;
        kacc += __expf(-(dx * dx + dy * dy + dz * dz) * INV2S);
        dx = ci0 - b4.z; dy = ci1 - b4.w; dz = ci2 - c4.x;
        kacc += __expf(-(dx * dx + dy * dy + dz * dz) * INV2S);
        dx = ci0 - c4.y; dy = ci1 - c4.z; dz = ci2 - c4.w;
        kacc += __expf(-(dx * dx + dy * dy + dz * dz) * INV2S);
      }
      kacc += __shfl_xor(kacc, 16);
      const float kde = COEF * kacc;
      float m = kde;
      m = fmaxf(m, __shfl_xor(m, 1));
      m = fmaxf(m, __shfl_xor(m, 2));
      m = fmaxf(m, __shfl_xor(m, 4));
      m = fmaxf(m, __shfl_xor(m, 8));
      const float s = (kde / (m + 1e-6f)) * (1.f / 16.f);

      const float* rbase = spk + g * 512 + i * 32;
      const int ix = i & 7;
      const f4 v0 = *reinterpret_cast<const f4*>(&rbase[(0 ^ ix) << 2]);
      const f4 v1 = *reinterpret_cast<const f4*>(&rbase[(1 ^ ix) << 2]);
      const f4 v2 = *reinterpret_cast<const f4*>(&rbase[(2 ^ ix) << 2]);
      const f4 v3 = *reinterpret_cast<const f4*>(&rbase[(3 ^ ix) << 2]);
      const f4 v4 = *reinterpret_cast<const f4*>(&rbase[(4 ^ ix) << 2]);
      const f4 v5 = *reinterpret_cast<const f4*>(&rbase[(5 ^ ix) << 2]);
      const f4 v6 = *reinterpret_cast<const f4*>(&rbase[(6 ^ ix) << 2]);
      const f4 v7 = *reinterpret_cast<const f4*>(&rbase[(7 ^ ix) << 2]);

      float o0 = 0.f, o1 = 0.f, o2 = 0.f;
      #pragma unroll
      for (int hh = 0; hh < 8; ++hh) {
        const int h = half * 8 + hh;
        const float4* Wr = reinterpret_cast<const float4*>(Wh1 + h * PE_);
        const float u = dot4(Wr[0], v0) + dot4(Wr[1], v1) + dot4(Wr[2], v2) +
                        dot4(Wr[3], v3) + dot4(Wr[4], v4) + dot4(Wr[5], v5) +
                        dot4(Wr[6], v6) + dot4(Wr[7], v7);
        const float a = fmaxf(fmaf(s, u, bh1[h]), 0.f);
        o0 = fmaf(Wh2[0 * HID_ + h], a, o0);
        o1 = fmaf(Wh2[1 * HID_ + h], a, o1);
        o2 = fmaf(Wh2[2 * HID_ + h], a, o2);
      }
      o0 += __shfl_xor(o0, 16);
      o1 += __shfl_xor(o1, 16);
      o2 += __shfl_xor(o2, 16);
      if (half == 0) {
        float* dp = delta + ((size_t)gid * K_ + i) * 3;
        dp[0] = o0 + bh2[0];
        dp[1] = o1 + bh2[1];
        dp[2] = o2 + bh2[2];
      }
    }
  }
}

extern "C" void kernel_launch(void* const* d_in, const int* in_sizes, int n_in,
                              void* d_out, int out_size, void* d_ws, size_t ws_size,
                              hipStream_t stream) {
  // setup_inputs() dict order: p, f, pe, W1, b1, Wpe, bpe, Wh1, bh1, Wh2, bh2, knn_idx
  const float* p   = (const float*)d_in[0];
  const float* f   = (const float*)d_in[1];
  const float* pe  = (const float*)d_in[2];
  const float* W1  = (const float*)d_in[3];
  const float* b1  = (const float*)d_in[4];
  const float* Wpe = (const float*)d_in[5];
  const float* bpe = (const float*)d_in[6];
  const float* Wh1 = (const float*)d_in[7];
  const float* bh1 = (const float*)d_in[8];
  const float* Wh2 = (const float*)d_in[9];
  const float* bh2 = (const float*)d_in[10];
  const int* knn   = (const int*)d_in[11];
  float* fout  = (float*)d_out;                        // [B,C,N]
  float* delta = (float*)d_out + (size_t)B_ * C_ * N_; // [B*N,K,3]
  float* ht = (float*)d_ws;                            // [B,N,C] = 4 MB

  k1v3<<<(B_ * N_) / 16, 256, 0, stream>>>(f, W1, b1, ht);
  k23_split<<<NP2 + (B_ * N_) / 8, 256, 0, stream>>>(
      p, pe, ht, knn, Wpe, bpe, Wh1, bh1, Wh2, bh2, fout, delta);
}

// Round 22
// 55.535 us; speedup vs baseline: 1.1773x; 1.1773x over previous
//
#include <hip/hip_runtime.h>

#define B_ 2
#define N_ 8192
#define K_ 16
#define C_ 64
#define PE_ 32
#define HID_ 16

typedef float f4 __attribute__((ext_vector_type(4)));

__device__ __forceinline__ f4 splat4(float x) { f4 r = {x, x, x, x}; return r; }
__device__ __forceinline__ f4 relu4(f4 v) {
  f4 r;
  r[0] = fmaxf(v[0], 0.f); r[1] = fmaxf(v[1], 0.f);
  r[2] = fmaxf(v[2], 0.f); r[3] = fmaxf(v[3], 0.f);
  return r;
}
__device__ __forceinline__ float dot4(float4 w, f4 v) {
  return fmaf(w.x, v[0], fmaf(w.y, v[1], fmaf(w.z, v[2], w.w * v[3])));
}

struct PK4 { f4 k0, k1, k2, k3; };

// pk[ii] = sum_j relu((Wd.c_ii + bd) - Wd.c_j), all 16 ii, named registers.
__device__ __forceinline__ PK4 channel(const float4* __restrict__ sq,
                                       int d, const float* __restrict__ Wpe,
                                       const float* __restrict__ bpe) {
  const float wx = Wpe[d * 3 + 0], wy = Wpe[d * 3 + 1], wz = Wpe[d * 3 + 2];
  const float wb = bpe[d];
  const float4 A0 = sq[0], B0 = sq[1], C0 = sq[2];
  const float4 A1 = sq[3], B1 = sq[4], C1 = sq[5];
  const float4 A2 = sq[6], B2 = sq[7], C2 = sq[8];
  const float4 A3 = sq[9], B3 = sq[10], C3 = sq[11];
  const float p0  = fmaf(wx, A0.x, fmaf(wy, A0.y, wz * A0.z));
  const float p1  = fmaf(wx, A0.w, fmaf(wy, B0.x, wz * B0.y));
  const float p2  = fmaf(wx, B0.z, fmaf(wy, B0.w, wz * C0.x));
  const float p3  = fmaf(wx, C0.y, fmaf(wy, C0.z, wz * C0.w));
  const float p4  = fmaf(wx, A1.x, fmaf(wy, A1.y, wz * A1.z));
  const float p5  = fmaf(wx, A1.w, fmaf(wy, B1.x, wz * B1.y));
  const float p6  = fmaf(wx, B1.z, fmaf(wy, B1.w, wz * C1.x));
  const float p7  = fmaf(wx, C1.y, fmaf(wy, C1.z, wz * C1.w));
  const float p8  = fmaf(wx, A2.x, fmaf(wy, A2.y, wz * A2.z));
  const float p9  = fmaf(wx, A2.w, fmaf(wy, B2.x, wz * B2.y));
  const float p10 = fmaf(wx, B2.z, fmaf(wy, B2.w, wz * C2.x));
  const float p11 = fmaf(wx, C2.y, fmaf(wy, C2.z, wz * C2.w));
  const float p12 = fmaf(wx, A3.x, fmaf(wy, A3.y, wz * A3.z));
  const float p13 = fmaf(wx, A3.w, fmaf(wy, B3.x, wz * B3.y));
  const float p14 = fmaf(wx, B3.z, fmaf(wy, B3.w, wz * C3.x));
  const float p15 = fmaf(wx, C3.y, fmaf(wy, C3.z, wz * C3.w));
  const f4 a0 = {p0 + wb, p1 + wb, p2 + wb, p3 + wb};
  const f4 a1 = {p4 + wb, p5 + wb, p6 + wb, p7 + wb};
  const f4 a2 = {p8 + wb, p9 + wb, p10 + wb, p11 + wb};
  const f4 a3 = {p12 + wb, p13 + wb, p14 + wb, p15 + wb};
  f4 k0 = splat4(0.f), k1 = splat4(0.f), k2 = splat4(0.f), k3 = splat4(0.f);
#define KSTEP(PJ)                                  \
  {                                                \
    const f4 sp = splat4(PJ);                      \
    k0 += relu4(a0 - sp); k1 += relu4(a1 - sp);    \
    k2 += relu4(a2 - sp); k3 += relu4(a3 - sp);    \
  }
  KSTEP(p0) KSTEP(p1) KSTEP(p2) KSTEP(p3) KSTEP(p4) KSTEP(p5) KSTEP(p6)
  KSTEP(p7) KSTEP(p8) KSTEP(p9) KSTEP(p10) KSTEP(p11) KSTEP(p12) KSTEP(p13)
  KSTEP(p14) KSTEP(p15)
#undef KSTEP
  PK4 r; r.k0 = k0; r.k1 = k1; r.k2 = k2; r.k3 = k3;
  return r;
}

// ---------------- Kernel 1 v3: LDS-staged coalesced f reads (R16 verbatim)
__global__ __launch_bounds__(256) void k1v3(
    const float* __restrict__ f, const float* __restrict__ W1,
    const float* __restrict__ b1, float* __restrict__ ht) {
  __shared__ float sf[C_ * 20];            // [64][20] floats, 5120 B
  const int t = threadIdx.x;
  const int g0 = blockIdx.x * 16;
  const int b = g0 >> 13;
  const int n0 = g0 & (N_ - 1);
  {
    const int c = t >> 2, off = (t & 3) * 4;
    const f4 v = *reinterpret_cast<const f4*>(f + (size_t)(b * C_ + c) * N_ + n0 + off);
    *reinterpret_cast<f4*>(&sf[c * 20 + off]) = v;
  }
  __syncthreads();
  const int lane = t & 63;
  const int w = t >> 6;
  const f4* wp = reinterpret_cast<const f4*>(W1 + lane * C_);
  const f4 w0 = wp[0], w1 = wp[1], w2 = wp[2], w3 = wp[3];
  const f4 w4 = wp[4], w5 = wp[5], w6 = wp[6], w7 = wp[7];
  const f4 w8 = wp[8], w9 = wp[9], w10 = wp[10], w11 = wp[11];
  const f4 w12 = wp[12], w13 = wp[13], w14 = wp[14], w15 = wp[15];
  f4 a = splat4(0.f);
#define CSTEP(Q, E)                                                         \
  {                                                                         \
    const f4 fv = *reinterpret_cast<const f4*>(&sf[(Q * 4 + E) * 20 + w * 4]); \
    a += splat4(w##Q[E]) * fv;                                              \
  }
#define CQ(Q) CSTEP(Q, 0) CSTEP(Q, 1) CSTEP(Q, 2) CSTEP(Q, 3)
  CQ(0) CQ(1) CQ(2) CQ(3) CQ(4) CQ(5) CQ(6) CQ(7)
  CQ(8) CQ(9) CQ(10) CQ(11) CQ(12) CQ(13) CQ(14) CQ(15)
#undef CQ
#undef CSTEP
  const float bias = b1[lane];
  #pragma unroll
  for (int pt = 0; pt < 4; ++pt)
    ht[(size_t)(b * N_ + n0 + w * 4 + pt) * C_ + lane] = fmaxf(a[pt] + bias, 0.f);
}

// ---------------- Kernel 2+3, block-range split (R20 champion verbatim):
// P2 coalesced-pe max-pool with plain (cacheable) pe loads; P3 parallel-channel.
#define SFJ_STRIDE 65
#define SOUT_OFF 16640
#define NP2 1024
__global__ __launch_bounds__(256) void k23_split(
    const float* __restrict__ p, const float* __restrict__ pe,
    const float* __restrict__ ht, const int* __restrict__ knn,
    const float* __restrict__ Wpe, const float* __restrict__ bpe,
    const float* __restrict__ Wh1, const float* __restrict__ bh1,
    const float* __restrict__ Wh2, const float* __restrict__ bh2,
    float* __restrict__ fout, float* __restrict__ delta) {
  __shared__ __align__(16) char smem[21760];
  const int t = threadIdx.x;

  if (blockIdx.x < NP2) {
    // ================= P2: fout = max_k(pe + gathered ht) ====
    float* sfj = (float*)smem;                 // [64][65] floats, 16640 B
    float* sout = (float*)(smem + SOUT_OFF);   // [64][20]
    const int base = blockIdx.x * 16;
    const int b = base >> 13;
    const int n0b = base & (N_ - 1);
    const int lane = t & 63;
    const int w = t >> 6;
    const int csub = lane >> 4, sl = lane & 15;
    const int j = sl & 3, nn = sl >> 2;
    #pragma unroll 1
    for (int si = 0; si < 4; ++si) {
      const int n0 = n0b + si * 4;
      #pragma unroll
      for (int n = 0; n < 4; ++n) {
        const int* kn = knn + (size_t)(b * N_ + n0 + n) * K_ + w * 4;  // uniform
        #pragma unroll
        for (int kk = 0; kk < 4; ++kk) {
          const int id = kn[kk];
          const float hv = ht[(size_t)(b * N_ + id) * C_ + lane];
          sfj[lane * SFJ_STRIDE + (n * 4 + w) * 4 + kk] = hv;
        }
      }
      __syncthreads();
      #pragma unroll
      for (int it2 = 0; it2 < 4; ++it2) {
        const int c = it2 * 16 + w * 4 + csub;
        const f4 pv = *(reinterpret_cast<const f4*>(
            pe + ((size_t)(b * C_ + c) * N_ + n0) * K_) + sl);   // plain load
        const f4 fj = *reinterpret_cast<const f4*>(&sfj[c * SFJ_STRIDE + sl * 4]);
        float v = fmaxf(fmaxf(pv[0] + fj[0], pv[1] + fj[1]),
                        fmaxf(pv[2] + fj[2], pv[3] + fj[3]));
        v = fmaxf(v, __shfl_xor(v, 1));
        v = fmaxf(v, __shfl_xor(v, 2));
        if (j == 0) sout[c * 20 + si * 4 + nn] = v;
      }
      __syncthreads();
    }
    const int c = t >> 2, q = t & 3;
    const float4 r = *reinterpret_cast<const float4*>(&sout[c * 20 + q * 4]);
    *reinterpret_cast<float4*>(fout + (size_t)(b * C_ + c) * N_ + n0b + q * 4) = r;
    return;
  }

  // ================= P3: KDE offset generator ==========
  {
    float* spk = (float*)smem;               // [8][16][32] quad-swizzled, 16 KB
    float* sc = (float*)(smem + 16384);      // [8][48] coords
    const int base = (blockIdx.x - NP2) * 8;
    const int b = base >> 13;
    const int g = t >> 5;
    const int l = t & 31;

    if (l < 16) {
      const int gid = base + g;
      const int idx = knn[(size_t)gid * K_ + l];
      const float* pp = p + (size_t)(b * N_ + idx) * 3;
      sc[g * 48 + l * 3 + 0] = pp[0];
      sc[g * 48 + l * 3 + 1] = pp[1];
      sc[g * 48 + l * 3 + 2] = pp[2];
    }
    __syncthreads();

    {
      const int d = l;
      const float4* sq = reinterpret_cast<const float4*>(&sc[g * 48]);
      const PK4 ck = channel(sq, d, Wpe, bpe);
      const int qw = d >> 2, pos = d & 3;
      float* gbase = spk + g * 512;
#define PKW(II, KV) \
      gbase[(II) * 32 + (((qw ^ ((II) & 7)) << 2) | pos)] = ck.KV[(II) & 3];
      PKW(0, k0) PKW(1, k0) PKW(2, k0) PKW(3, k0)
      PKW(4, k1) PKW(5, k1) PKW(6, k1) PKW(7, k1)
      PKW(8, k2) PKW(9, k2) PKW(10, k2) PKW(11, k2)
      PKW(12, k3) PKW(13, k3) PKW(14, k3) PKW(15, k3)
#undef PKW
    }
    __syncthreads();

    {
      const int i = t & 15, half = (t >> 4) & 1;
      const int gid = base + g;
      const float ci0 = sc[g * 48 + i * 3 + 0];
      const float ci1 = sc[g * 48 + i * 3 + 1];
      const float ci2 = sc[g * 48 + i * 3 + 2];
      const float4* sq = reinterpret_cast<const float4*>(&sc[g * 48]);
      const float INV2S = 0.49999975f;
      const float COEF = 0.39894225f;
      float kacc = 0.f;
      #pragma unroll
      for (int jj = 0; jj < 2; ++jj) {
        const int j4 = half * 2 + jj;
        const float4 a = sq[j4 * 3 + 0], b4 = sq[j4 * 3 + 1], c4 = sq[j4 * 3 + 2];
        float dx, dy, dz;
        dx = ci0 - a.x;  dy = ci1 - a.y;  dz = ci2 - a.z;
        kacc += __expf(-(dx * dx + dy * dy + dz * dz) * INV2S);
        dx = ci0 - a.w;  dy = ci1 - b4.x; dz = ci2 - b4.y;
        kacc += __expf(-(dx * dx + dy * dy + dz * dz) * INV2S);
        dx = ci0 - b4.z; dy = ci1 - b4.w; dz = ci2 - c4.x;
        kacc += __expf(-(dx * dx + dy * dy + dz * dz) * INV2S);
        dx = ci0 - c4.y; dy = ci1 - c4.z; dz = ci2 - c4.w;
        kacc += __expf(-(dx * dx + dy * dy + dz * dz) * INV2S);
      }
      kacc += __shfl_xor(kacc, 16);
      const float kde = COEF * kacc;
      float m = kde;
      m = fmaxf(m, __shfl_xor(m, 1));
      m = fmaxf(m, __shfl_xor(m, 2));
      m = fmaxf(m, __shfl_xor(m, 4));
      m = fmaxf(m, __shfl_xor(m, 8));
      const float s = (kde / (m + 1e-6f)) * (1.f / 16.f);

      const float* rbase = spk + g * 512 + i * 32;
      const int ix = i & 7;
      const f4 v0 = *reinterpret_cast<const f4*>(&rbase[(0 ^ ix) << 2]);
      const f4 v1 = *reinterpret_cast<const f4*>(&rbase[(1 ^ ix) << 2]);
      const f4 v2 = *reinterpret_cast<const f4*>(&rbase[(2 ^ ix) << 2]);
      const f4 v3 = *reinterpret_cast<const f4*>(&rbase[(3 ^ ix) << 2]);
      const f4 v4 = *reinterpret_cast<const f4*>(&rbase[(4 ^ ix) << 2]);
      const f4 v5 = *reinterpret_cast<const f4*>(&rbase[(5 ^ ix) << 2]);
      const f4 v6 = *reinterpret_cast<const f4*>(&rbase[(6 ^ ix) << 2]);
      const f4 v7 = *reinterpret_cast<const f4*>(&rbase[(7 ^ ix) << 2]);

      float o0 = 0.f, o1 = 0.f, o2 = 0.f;
      #pragma unroll
      for (int hh = 0; hh < 8; ++hh) {
        const int h = half * 8 + hh;
        const float4* Wr = reinterpret_cast<const float4*>(Wh1 + h * PE_);
        const float u = dot4(Wr[0], v0) + dot4(Wr[1], v1) + dot4(Wr[2], v2) +
                        dot4(Wr[3], v3) + dot4(Wr[4], v4) + dot4(Wr[5], v5) +
                        dot4(Wr[6], v6) + dot4(Wr[7], v7);
        const float a = fmaxf(fmaf(s, u, bh1[h]), 0.f);
        o0 = fmaf(Wh2[0 * HID_ + h], a, o0);
        o1 = fmaf(Wh2[1 * HID_ + h], a, o1);
        o2 = fmaf(Wh2[2 * HID_ + h], a, o2);
      }
      o0 += __shfl_xor(o0, 16);
      o1 += __shfl_xor(o1, 16);
      o2 += __shfl_xor(o2, 16);
      if (half == 0) {
        float* dp = delta + ((size_t)gid * K_ + i) * 3;
        dp[0] = o0 + bh2[0];
        dp[1] = o1 + bh2[1];
        dp[2] = o2 + bh2[2];
      }
    }
  }
}

extern "C" void kernel_launch(void* const* d_in, const int* in_sizes, int n_in,
                              void* d_out, int out_size, void* d_ws, size_t ws_size,
                              hipStream_t stream) {
  // setup_inputs() dict order: p, f, pe, W1, b1, Wpe, bpe, Wh1, bh1, Wh2, bh2, knn_idx
  const float* p   = (const float*)d_in[0];
  const float* f   = (const float*)d_in[1];
  const float* pe  = (const float*)d_in[2];
  const float* W1  = (const float*)d_in[3];
  const float* b1  = (const float*)d_in[4];
  const float* Wpe = (const float*)d_in[5];
  const float* bpe = (const float*)d_in[6];
  const float* Wh1 = (const float*)d_in[7];
  const float* bh1 = (const float*)d_in[8];
  const float* Wh2 = (const float*)d_in[9];
  const float* bh2 = (const float*)d_in[10];
  const int* knn   = (const int*)d_in[11];
  float* fout  = (float*)d_out;                        // [B,C,N]
  float* delta = (float*)d_out + (size_t)B_ * C_ * N_; // [B*N,K,3]
  float* ht = (float*)d_ws;                            // [B,N,C] = 4 MB

  k1v3<<<(B_ * N_) / 16, 256, 0, stream>>>(f, W1, b1, ht);
  k23_split<<<NP2 + (B_ * N_) / 8, 256, 0, stream>>>(
      p, pe, ht, knn, Wpe, bpe, Wh1, bh1, Wh2, bh2, fout, delta);
}